// Round 2
// baseline (392.526 us; speedup 1.0000x reference)
//
#include <hip/hip_runtime.h>

typedef unsigned short u16;
typedef __bf16 bf8 __attribute__((ext_vector_type(8)));
typedef float f4 __attribute__((ext_vector_type(4)));

#define E_EDGES 32768
#define N_NODES 4096
// col layout of w (WNUM=6400): A[u<64][w<64] @0, B[u<64][w<16] @4096, C[u<16][w<16] @5120, D[u<16][w<64] @5376
#define N0_CONST 0.1118033988749895f       // sqrt(1/80); also equals N1*INV_SQRT3
#define INV_SQRT3_CONST 0.5773502691896258f

__device__ __forceinline__ u16 f2bf(float f) {
    unsigned u = __float_as_uint(f);
    u += 0x7FFFu + ((u >> 16) & 1u);   // RNE
    return (u16)(u >> 16);
}

// Transpose-convert: src fp32 [128][C] -> dst bf16 [C][128]
__global__ void k_transpose(const float* __restrict__ src, u16* __restrict__ dst, int C) {
    __shared__ float tile[32][33];
    int bx = blockIdx.x, by = blockIdx.y;
    int tx = threadIdx.x, ty = threadIdx.y;
    int c = bx * 32 + tx;
#pragma unroll
    for (int r = 0; r < 4; r++) {
        int k = by * 32 + ty + r * 8;
        tile[ty + r * 8][tx] = src[k * C + c];
    }
    __syncthreads();
#pragma unroll
    for (int r = 0; r < 4; r++) {
        int cc = bx * 32 + ty + r * 8;
        dst[cc * 128 + by * 32 + tx] = f2bf(tile[tx][ty + r * 8]);
    }
}

// h = relu(edge_attr @ W1 + b1), stored bf16 [E][128]
__global__ __launch_bounds__(256) void k_h(const float* __restrict__ ea,
                                           const u16* __restrict__ w1t,
                                           const float* __restrict__ b1,
                                           u16* __restrict__ h) {
    __shared__ alignas(16) u16 ea_s[64][128];
    int tid = threadIdx.x;
    int e0 = blockIdx.x * 64;
    {
        int e = tid >> 2, q = tid & 3;
        const float4* src = (const float4*)(ea + (size_t)(e0 + e) * 128 + q * 32);
#pragma unroll
        for (int i = 0; i < 8; i++) {
            float4 f = src[i];
            int c = q * 32 + i * 4;
            ea_s[e][c + 0] = f2bf(f.x); ea_s[e][c + 1] = f2bf(f.y);
            ea_s[e][c + 2] = f2bf(f.z); ea_s[e][c + 3] = f2bf(f.w);
        }
    }
    __syncthreads();
    int lane = tid & 63, wave = tid >> 6;
    int el = lane & 15, q4 = lane >> 4;
    f4 acc[4][2];
#pragma unroll
    for (int m = 0; m < 4; m++)
#pragma unroll
        for (int nt = 0; nt < 2; nt++) acc[m][nt] = (f4){0.f, 0.f, 0.f, 0.f};
#pragma unroll
    for (int ks = 0; ks < 4; ks++) {
        bf8 a[4], b[2];
#pragma unroll
        for (int m = 0; m < 4; m++) a[m] = *(const bf8*)&ea_s[m * 16 + el][ks * 32 + q4 * 8];
#pragma unroll
        for (int nt = 0; nt < 2; nt++) {
            int n = wave * 32 + nt * 16 + el;
            b[nt] = *(const bf8*)(w1t + n * 128 + ks * 32 + q4 * 8);
        }
#pragma unroll
        for (int m = 0; m < 4; m++)
#pragma unroll
            for (int nt = 0; nt < 2; nt++)
                acc[m][nt] = __builtin_amdgcn_mfma_f32_16x16x32_bf16(a[m], b[nt], acc[m][nt], 0, 0, 0);
    }
#pragma unroll
    for (int m = 0; m < 4; m++)
#pragma unroll
        for (int nt = 0; nt < 2; nt++) {
            int n = wave * 32 + nt * 16 + el;
            float bias = b1[n];
#pragma unroll
            for (int r = 0; r < 4; r++) {
                int e = e0 + m * 16 + q4 * 4 + r;
                float v = fmaxf(acc[m][nt][r] + bias, 0.f);
                h[(size_t)e * 128 + n] = f2bf(v);
            }
        }
}

// Fused: w = h@W2+b2 (tile-by-tile, never materialized) -> contraction -> scatter-atomics into sums.
// 512 threads = 8 waves. Wave-pair (2w,2w+1) shares m-group w (m-stride 4); each wave owns 32 edges.
// VGPR budget ~115 -> fits __launch_bounds__(512,4) => 2 blocks/CU = 16 waves/CU.
__global__ __launch_bounds__(512, 4) void k_main(const u16* __restrict__ w2t,
                                                 const u16* __restrict__ hgl,
                                                 const float* __restrict__ b2,
                                                 const float* __restrict__ node_attr,
                                                 const int* __restrict__ edge_index,
                                                 const float* __restrict__ edge_sh,
                                                 float* __restrict__ sums,
                                                 float* __restrict__ cnt) {
    __shared__ alignas(16) u16 h_s[64][128];   // 16 KB
    __shared__ float sT[64][64];               // 16 KB  s[u][e]
    __shared__ float vT[3][16][64];            // 12 KB  v[i][u][e]
    __shared__ float pT[16][66];               // 4.1 KB INV_SQRT3*(v.sh1)[u][e]; reused as redB (pad->2-way)
    __shared__ float accC_s[48][66];           // 12.4KB C_pre[i*16+w'][e] (pad->2-way)
    __shared__ float sh0_s[64];
    __shared__ float sh1_s[3][64];
    __shared__ int src_s[64];
    __shared__ int dst_s[64];

    int tid = threadIdx.x;
    int e0 = blockIdx.x * 64;

    // phase 1: edge meta + zero accC
    if (tid < 64) {
        int ge = e0 + tid;
        src_s[tid] = edge_index[ge];
        dst_s[tid] = edge_index[E_EDGES + ge];
        float4 sh = *(const float4*)(edge_sh + (size_t)ge * 4);
        sh0_s[tid] = sh.x; sh1_s[0][tid] = sh.y; sh1_s[1][tid] = sh.z; sh1_s[2][tid] = sh.w;
    } else {
        int t = tid - 64;
        for (int i = t; i < 48 * 66; i += 448) ((float*)accC_s)[i] = 0.f;
    }
    __syncthreads();

    // phase 2: threads 0..255 load node features (transposed); 256..511 copy the h tile
    if (tid < 256) {
        int e = tid >> 2, q = tid & 3;
        int dst = dst_s[e];
        const float* xp = node_attr + (size_t)dst * 112;
#pragma unroll
        for (int i = 0; i < 4; i++) {
            float4 f = *(const float4*)(xp + q * 16 + i * 4);
            int u = q * 16 + i * 4;
            sT[u + 0][e] = f.x; sT[u + 1][e] = f.y; sT[u + 2][e] = f.z; sT[u + 3][e] = f.w;
        }
        float vv[12];
#pragma unroll
        for (int i = 0; i < 3; i++) {
            float4 f = *(const float4*)(xp + 64 + q * 12 + i * 4);
            vv[i * 4 + 0] = f.x; vv[i * 4 + 1] = f.y; vv[i * 4 + 2] = f.z; vv[i * 4 + 3] = f.w;
        }
        float s1x = sh1_s[0][e], s1y = sh1_s[1][e], s1z = sh1_s[2][e];
#pragma unroll
        for (int u = 0; u < 4; u++) {
            float xa = vv[u * 3 + 0], xb = vv[u * 3 + 1], xc = vv[u * 3 + 2];
            int uu = q * 4 + u;
            vT[0][uu][e] = xa; vT[1][uu][e] = xb; vT[2][uu][e] = xc;
            pT[uu][e] = INV_SQRT3_CONST * (xa * s1x + xb * s1y + xc * s1z);
        }
    } else {
        int t = tid - 256;
        int e = t >> 2, q = t & 3;
        const uint4* hsrc = (const uint4*)(hgl + (size_t)(e0 + e) * 128) + q * 4;
        uint4* hdst = (uint4*)(&h_s[e][q * 32]);
#pragma unroll
        for (int i = 0; i < 4; i++) hdst[i] = hsrc[i];
    }
    __syncthreads();

    int lane = tid & 63, wave = tid >> 6;
    int el = lane & 15, q4 = lane >> 4;
    int grp = wave >> 1;         // m-group 0..3
    int eh = wave & 1;           // edge-half 0..1

    // B-fragments (h) resident for whole block: 2 n-tiles only -> 32 VGPRs
    bf8 hb[2][4];
#pragma unroll
    for (int n = 0; n < 2; n++)
#pragma unroll
        for (int ks = 0; ks < 4; ks++)
            hb[n][ks] = *(const bf8*)&h_s[eh * 32 + n * 16 + el][ks * 32 + q4 * 8];
    float sh0n[2];
#pragma unroll
    for (int n = 0; n < 2; n++) sh0n[n] = sh0_s[eh * 32 + n * 16 + el];

    f4 acc0[2], accB[2];
#pragma unroll
    for (int n = 0; n < 2; n++) { acc0[n] = (f4){0.f,0.f,0.f,0.f}; accB[n] = (f4){0.f,0.f,0.f,0.f}; }

    const int alo = el * 128 + q4 * 8;   // lane offset within a 16x128 A-slab (in u16)
    bf8 af[4]; float4 b2f;
    {
        const u16* p = w2t + (size_t)grp * 2048 + alo;
#pragma unroll
        for (int ks = 0; ks < 4; ks++) af[ks] = *(const bf8*)(p + ks * 32);
        b2f = *(const float4*)(b2 + grp * 16 + q4 * 4);
    }

    for (int mt = grp; mt < 400; mt += 4) {
        int mtn = (mt + 4 < 400) ? (mt + 4) : mt;
        bf8 afn[4]; float4 b2fn;
        {
            const u16* p = w2t + (size_t)mtn * 2048 + alo;
#pragma unroll
            for (int ks = 0; ks < 4; ks++) afn[ks] = *(const bf8*)(p + ks * 32);
            b2fn = *(const float4*)(b2 + mtn * 16 + q4 * 4);
        }
        f4 wf[2];
#pragma unroll
        for (int n = 0; n < 2; n++) wf[n] = (f4){b2f.x, b2f.y, b2f.z, b2f.w};
#pragma unroll
        for (int ks = 0; ks < 4; ks++)
#pragma unroll
            for (int n = 0; n < 2; n++)
                wf[n] = __builtin_amdgcn_mfma_f32_16x16x32_bf16(af[ks], hb[n][ks], wf[n], 0, 0, 0);

        int c0 = mt * 16;
        if (c0 < 4096) {                    // A: scale sh0*s[u], out0 rows grp*16..+16
            int u = c0 >> 6;
#pragma unroll
            for (int n = 0; n < 2; n++) {
                float sv = sh0n[n] * sT[u][eh * 32 + n * 16 + el];
                acc0[n] += sv * wf[n];
            }
        } else if (c0 < 5120) {             // B: scale s[u], 16 rows (cross-wave partial)
            int u = (c0 - 4096) >> 4;
#pragma unroll
            for (int n = 0; n < 2; n++) {
                float sv = sT[u][eh * 32 + n * 16 + el];
                accB[n] += sv * wf[n];
            }
        } else if (c0 < 5376) {             // C: scales v[i][u], into LDS (cross-wave partial)
            int u = (c0 - 5120) >> 4;
#pragma unroll
            for (int n = 0; n < 2; n++) {
                int e = eh * 32 + n * 16 + el;
#pragma unroll
                for (int i = 0; i < 3; i++) {
                    float sv = vT[i][u][e];
#pragma unroll
                    for (int r = 0; r < 4; r++)
                        unsafeAtomicAdd(&accC_s[i * 16 + q4 * 4 + r][e], sv * wf[n][r]);
                }
            }
        } else {                            // D: scale p[u], out0 rows grp*16..+16
            int u = (c0 - 5376) >> 6;
#pragma unroll
            for (int n = 0; n < 2; n++) {
                float sv = pT[u][eh * 32 + n * 16 + el];
                acc0[n] += sv * wf[n];
            }
        }
#pragma unroll
        for (int ks = 0; ks < 4; ks++) af[ks] = afn[ks];
        b2f = b2fn;
    }

    // out0 scatter: wave owns rows [grp*16, grp*16+16) for its 32 edges
#pragma unroll
    for (int n = 0; n < 2; n++) {
        int e = eh * 32 + n * 16 + el;
        int base = src_s[e] * 112 + grp * 16 + q4 * 4;
#pragma unroll
        for (int r = 0; r < 4; r++)
            unsafeAtomicAdd(&sums[base + r], N0_CONST * acc0[n][r]);
    }
    __syncthreads();               // M-loop + accC complete everywhere; pT dead -> reuse as redB
    for (int i = tid; i < 16 * 66; i += 512) ((float*)pT)[i] = 0.f;
    __syncthreads();
#pragma unroll
    for (int n = 0; n < 2; n++) {
        int e = eh * 32 + n * 16 + el;
#pragma unroll
        for (int r = 0; r < 4; r++)
            unsafeAtomicAdd(&pT[q4 * 4 + r][e], accB[n][r]);
    }
    __syncthreads();
    // out1 scatter: col 64 + w'*3 + i = C1*(B_pre[w']*sh1[i] + C_pre[i][w']*sh0), C1 = N1*INV_SQRT3 = N0
    for (int idx = tid; idx < 64 * 48; idx += 512) {
        int e = idx / 48;
        int cr = idx - e * 48;
        int wp = cr / 3;
        int i = cr - wp * 3;
        float val = N0_CONST * (pT[wp][e] * sh1_s[i][e] + accC_s[i * 16 + wp][e] * sh0_s[e]);
        unsafeAtomicAdd(&sums[src_s[e] * 112 + 64 + cr], val);
    }
    if (tid < 64) unsafeAtomicAdd(&cnt[src_s[tid]], 1.0f);
}

__global__ void k_final(const float* __restrict__ sums, const float* __restrict__ cnt,
                        const float* __restrict__ node_attr, float* __restrict__ out) {
    int idx = blockIdx.x * 256 + threadIdx.x;
    if (idx < N_NODES * 112) {
        int n = idx / 112;
        float c = fmaxf(cnt[n], 1.f);
        out[idx] = sums[idx] / c + node_attr[idx];
    }
}

extern "C" void kernel_launch(void* const* d_in, const int* in_sizes, int n_in,
                              void* d_out, int out_size, void* d_ws, size_t ws_size,
                              hipStream_t stream) {
    const float* node_attr  = (const float*)d_in[0];
    const int*   edge_index = (const int*)d_in[1];
    const float* edge_attr  = (const float*)d_in[2];
    const float* edge_sh    = (const float*)d_in[3];
    const float* W1         = (const float*)d_in[6];
    const float* b1         = (const float*)d_in[7];
    const float* W2         = (const float*)d_in[8];
    const float* b2         = (const float*)d_in[9];
    float* out = (float*)d_out;

    char* ws = (char*)d_ws;
    u16*   w2t  = (u16*)ws;                       // 6400*128*2 = 1,638,400
    u16*   w1t  = (u16*)(ws + 1638400);           // 128*128*2  =    32,768
    u16*   hgl  = (u16*)(ws + 1671168);           // 32768*128*2 = 8,388,608
    float* sums = (float*)(ws + 10059776);        // 4096*112*4 = 1,835,008
    float* cnt  = (float*)(ws + 11894784);        // 4096*4     =    16,384

    hipMemsetAsync(sums, 0, 1835008 + 16384, stream);
    k_transpose<<<dim3(200, 4), dim3(32, 8), 0, stream>>>(W2, w2t, 6400);
    k_transpose<<<dim3(4, 4), dim3(32, 8), 0, stream>>>(W1, w1t, 128);
    k_h<<<512, 256, 0, stream>>>(edge_attr, w1t, b1, hgl);
    k_main<<<512, 512, 0, stream>>>(w2t, hgl, b2, node_attr, edge_index, edge_sh, sums, cnt);
    k_final<<<1792, 256, 0, stream>>>(sums, cnt, node_attr, out);
}

// Round 3
// 288.346 us; speedup vs baseline: 1.3613x; 1.3613x over previous
//
#include <hip/hip_runtime.h>

typedef unsigned short u16;
typedef __bf16 bf8 __attribute__((ext_vector_type(8)));
typedef float f4 __attribute__((ext_vector_type(4)));

#define E_EDGES 32768
#define N_NODES 4096
// col layout of w (WNUM=6400): A[u<64][w<64] @0, B[u<64][w<16] @4096, C[u<16][w<16] @5120, D[u<16][w<64] @5376
#define N0_CONST 0.1118033988749895f       // sqrt(1/80); also equals N1*INV_SQRT3
#define INV_SQRT3_CONST 0.5773502691896258f

__device__ __forceinline__ u16 f2bf(float f) {
    unsigned u = __float_as_uint(f);
    u += 0x7FFFu + ((u >> 16) & 1u);   // RNE
    return (u16)(u >> 16);
}

// Weight prep, one launch:
//  blocks 0..399:  w2s fragment-order swizzle: w2s[mt*2048 + ks*512 + l*8 + j] =
//                  bf16(W2[(ks*32+(l>>4)*8+j)*6400 + mt*16+(l&15)])  -> af loads become 1KB contiguous/wave
//  blocks 400..415: w1t[c*128+k] = bf16(W1[k*128+c])
__global__ __launch_bounds__(256) void k_prep(const float* __restrict__ W2, const float* __restrict__ W1,
                                              u16* __restrict__ w2s, u16* __restrict__ w1t) {
    int b = blockIdx.x;
    int tid = threadIdx.x;
    if (b < 400) {
        int ks = tid >> 6, l = tid & 63;
        int el = l & 15, q4 = l >> 4;
        int c = b * 16 + el;
        u16 tmp[8];
#pragma unroll
        for (int j = 0; j < 8; j++) {
            int k = ks * 32 + q4 * 8 + j;
            tmp[j] = f2bf(W2[(size_t)k * 6400 + c]);
        }
        *(uint4*)(w2s + b * 2048 + ks * 512 + l * 8) = *(uint4*)tmp;
    } else {
        int t = (b - 400) * 256 + tid;
#pragma unroll
        for (int i = 0; i < 4; i++) {
            int idx = t * 4 + i;                // idx = c*128 + k
            int c = idx >> 7, k = idx & 127;
            w1t[idx] = f2bf(W1[k * 128 + c]);
        }
    }
}

// h = relu(edge_attr @ W1 + b1), stored bf16 [E][128]; also zeroes sums+cnt (runs before k_main)
__global__ __launch_bounds__(256) void k_h(const float* __restrict__ ea,
                                           const u16* __restrict__ w1t,
                                           const float* __restrict__ b1,
                                           u16* __restrict__ h,
                                           float* __restrict__ zbuf) {
    {   // zero sums (458752) + cnt (4096) = 462848 floats over 131072 threads
        int gid = blockIdx.x * 256 + threadIdx.x;
        for (int i = gid; i < 462848; i += 131072) zbuf[i] = 0.f;
    }
    __shared__ alignas(16) u16 ea_s[64][128];
    int tid = threadIdx.x;
    int e0 = blockIdx.x * 64;
    {
        int e = tid >> 2, q = tid & 3;
        const float4* src = (const float4*)(ea + (size_t)(e0 + e) * 128 + q * 32);
#pragma unroll
        for (int i = 0; i < 8; i++) {
            float4 f = src[i];
            int c = q * 32 + i * 4;
            ea_s[e][c + 0] = f2bf(f.x); ea_s[e][c + 1] = f2bf(f.y);
            ea_s[e][c + 2] = f2bf(f.z); ea_s[e][c + 3] = f2bf(f.w);
        }
    }
    __syncthreads();
    int lane = tid & 63, wave = tid >> 6;
    int el = lane & 15, q4 = lane >> 4;
    f4 acc[4][2];
#pragma unroll
    for (int m = 0; m < 4; m++)
#pragma unroll
        for (int nt = 0; nt < 2; nt++) acc[m][nt] = (f4){0.f, 0.f, 0.f, 0.f};
#pragma unroll
    for (int ks = 0; ks < 4; ks++) {
        bf8 a[4], b[2];
#pragma unroll
        for (int m = 0; m < 4; m++) a[m] = *(const bf8*)&ea_s[m * 16 + el][ks * 32 + q4 * 8];
#pragma unroll
        for (int nt = 0; nt < 2; nt++) {
            int n = wave * 32 + nt * 16 + el;
            b[nt] = *(const bf8*)(w1t + n * 128 + ks * 32 + q4 * 8);
        }
#pragma unroll
        for (int m = 0; m < 4; m++)
#pragma unroll
            for (int nt = 0; nt < 2; nt++)
                acc[m][nt] = __builtin_amdgcn_mfma_f32_16x16x32_bf16(a[m], b[nt], acc[m][nt], 0, 0, 0);
    }
#pragma unroll
    for (int m = 0; m < 4; m++)
#pragma unroll
        for (int nt = 0; nt < 2; nt++) {
            int n = wave * 32 + nt * 16 + el;
            float bias = b1[n];
#pragma unroll
            for (int r = 0; r < 4; r++) {
                int e = e0 + m * 16 + q4 * 4 + r;
                float v = fmaxf(acc[m][nt][r] + bias, 0.f);
                h[(size_t)e * 128 + n] = f2bf(v);
            }
        }
}

// Fused: w = h@W2+b2 (tile-by-tile) -> contraction -> scatter-atomics.
// 256 threads = 4 waves; wave = m-group (stride 4, 100 iters); A-fragments from fragment-order w2s
// (1KB contiguous per wave-load). h_s overlaid with accC/redB -> 50 KB LDS -> 3 blocks/CU.
__global__ __launch_bounds__(256, 3) void k_main(const u16* __restrict__ w2s,
                                                 const u16* __restrict__ hgl,
                                                 const float* __restrict__ b2,
                                                 const float* __restrict__ node_attr,
                                                 const int* __restrict__ edge_index,
                                                 const float* __restrict__ edge_sh,
                                                 float* __restrict__ sums,
                                                 float* __restrict__ cnt) {
    __shared__ union {
        u16 h[64][128];                                    // 16384 B (prologue only)
        struct { float accC[48][66]; float redB[16][66]; } a;  // 16896 B (M-loop + epilogue)
    } ovl;
    __shared__ float sT[64][64];               // 16 KB  s[u][e]
    __shared__ float vT[3][16][64];            // 12 KB  v[i][u][e]
    __shared__ float pT[16][64];               // 4 KB   INV_SQRT3*(v.sh1)[u][e]
    __shared__ float sh0_s[64];
    __shared__ float sh1_s[3][64];
    __shared__ int src_s[64];
    __shared__ int dst_s[64];

    int tid = threadIdx.x;
    int e0 = blockIdx.x * 64;

    // phase 1: edge meta
    if (tid < 64) {
        int ge = e0 + tid;
        src_s[tid] = edge_index[ge];
        dst_s[tid] = edge_index[E_EDGES + ge];
        float4 sh = *(const float4*)(edge_sh + (size_t)ge * 4);
        sh0_s[tid] = sh.x; sh1_s[0][tid] = sh.y; sh1_s[1][tid] = sh.z; sh1_s[2][tid] = sh.w;
    }
    __syncthreads();

    // phase 2: node features (transposed into LDS) + h tile into ovl.h
    {
        int e = tid >> 2, q = tid & 3;
        int dst = dst_s[e];
        const float* xp = node_attr + (size_t)dst * 112;
#pragma unroll
        for (int i = 0; i < 4; i++) {
            float4 f = *(const float4*)(xp + q * 16 + i * 4);
            int u = q * 16 + i * 4;
            sT[u + 0][e] = f.x; sT[u + 1][e] = f.y; sT[u + 2][e] = f.z; sT[u + 3][e] = f.w;
        }
        float vv[12];
#pragma unroll
        for (int i = 0; i < 3; i++) {
            float4 f = *(const float4*)(xp + 64 + q * 12 + i * 4);
            vv[i * 4 + 0] = f.x; vv[i * 4 + 1] = f.y; vv[i * 4 + 2] = f.z; vv[i * 4 + 3] = f.w;
        }
        float s1x = sh1_s[0][e], s1y = sh1_s[1][e], s1z = sh1_s[2][e];
#pragma unroll
        for (int u = 0; u < 4; u++) {
            float xa = vv[u * 3 + 0], xb = vv[u * 3 + 1], xc = vv[u * 3 + 2];
            int uu = q * 4 + u;
            vT[0][uu][e] = xa; vT[1][uu][e] = xb; vT[2][uu][e] = xc;
            pT[uu][e] = INV_SQRT3_CONST * (xa * s1x + xb * s1y + xc * s1z);
        }
        const uint4* hsrc = (const uint4*)(hgl + (size_t)(e0 + e) * 128) + q * 4;
        uint4* hdst = (uint4*)(&ovl.h[e][q * 32]);
#pragma unroll
        for (int i = 0; i < 4; i++) hdst[i] = hsrc[i];
    }
    __syncthreads();

    int lane = tid & 63, wave = tid >> 6;
    int el = lane & 15, q4 = lane >> 4;

    // B-fragments (h) resident for whole block
    bf8 hb[4][4];
#pragma unroll
    for (int n = 0; n < 4; n++)
#pragma unroll
        for (int ks = 0; ks < 4; ks++)
            hb[n][ks] = *(const bf8*)&ovl.h[n * 16 + el][ks * 32 + q4 * 8];
    float sh0n[4];
#pragma unroll
    for (int n = 0; n < 4; n++) sh0n[n] = sh0_s[n * 16 + el];
    __syncthreads();   // everyone done reading ovl.h; overlay becomes accC/redB

    // zero accC + redB (contiguous, 4224 floats)
    for (int i = tid; i < 4224; i += 256) ((float*)&ovl.a)[i] = 0.f;
    __syncthreads();

    f4 acc0[4], accB[4];
#pragma unroll
    for (int n = 0; n < 4; n++) { acc0[n] = (f4){0.f,0.f,0.f,0.f}; accB[n] = (f4){0.f,0.f,0.f,0.f}; }

    const u16* abase = w2s + lane * 8;  // + mt*2048 + ks*512 : fully coalesced 1KB/wave-load
    bf8 af[4]; float4 b2f;
    {
        const u16* p = abase + (size_t)wave * 2048;
#pragma unroll
        for (int ks = 0; ks < 4; ks++) af[ks] = *(const bf8*)(p + ks * 512);
        b2f = *(const float4*)(b2 + wave * 16 + q4 * 4);
    }

    for (int mt = wave; mt < 400; mt += 4) {
        int mtn = (mt + 4 < 400) ? (mt + 4) : mt;
        bf8 afn[4]; float4 b2fn;
        {
            const u16* p = abase + (size_t)mtn * 2048;
#pragma unroll
            for (int ks = 0; ks < 4; ks++) afn[ks] = *(const bf8*)(p + ks * 512);
            b2fn = *(const float4*)(b2 + mtn * 16 + q4 * 4);
        }
        f4 wf[4];
#pragma unroll
        for (int n = 0; n < 4; n++) wf[n] = (f4){b2f.x, b2f.y, b2f.z, b2f.w};
#pragma unroll
        for (int ks = 0; ks < 4; ks++)
#pragma unroll
            for (int n = 0; n < 4; n++)
                wf[n] = __builtin_amdgcn_mfma_f32_16x16x32_bf16(af[ks], hb[n][ks], wf[n], 0, 0, 0);

        int c0 = mt * 16;
        if (c0 < 4096) {                    // A: scale sh0*s[u], out0 rows wave*16..+16
            int u = c0 >> 6;
#pragma unroll
            for (int n = 0; n < 4; n++) {
                float sv = sh0n[n] * sT[u][n * 16 + el];
                acc0[n] += sv * wf[n];
            }
        } else if (c0 < 5120) {             // B: scale s[u] (cross-wave partial)
            int u = (c0 - 4096) >> 4;
#pragma unroll
            for (int n = 0; n < 4; n++) {
                float sv = sT[u][n * 16 + el];
                accB[n] += sv * wf[n];
            }
        } else if (c0 < 5376) {             // C: scales v[i][u], into LDS (cross-wave partial)
            int u = (c0 - 5120) >> 4;
#pragma unroll
            for (int n = 0; n < 4; n++) {
                int e = n * 16 + el;
#pragma unroll
                for (int i = 0; i < 3; i++) {
                    float sv = vT[i][u][e];
#pragma unroll
                    for (int r = 0; r < 4; r++)
                        unsafeAtomicAdd(&ovl.a.accC[i * 16 + q4 * 4 + r][e], sv * wf[n][r]);
                }
            }
        } else {                            // D: scale p[u], out0 rows wave*16..+16
            int u = (c0 - 5376) >> 6;
#pragma unroll
            for (int n = 0; n < 4; n++) {
                float sv = pT[u][n * 16 + el];
                acc0[n] += sv * wf[n];
            }
        }
#pragma unroll
        for (int ks = 0; ks < 4; ks++) af[ks] = afn[ks];
        b2f = b2fn;
    }

    // out0 scatter: each wave owns complete rows [wave*16, wave*16+16)
#pragma unroll
    for (int n = 0; n < 4; n++) {
        int e = n * 16 + el;
        int base = src_s[e] * 112 + wave * 16 + q4 * 4;
#pragma unroll
        for (int r = 0; r < 4; r++)
            unsafeAtomicAdd(&sums[base + r], N0_CONST * acc0[n][r]);
    }
    // accB partials -> redB (disjoint LDS region; safe concurrent with other waves' accC atomics)
#pragma unroll
    for (int n = 0; n < 4; n++) {
        int e = n * 16 + el;
#pragma unroll
        for (int r = 0; r < 4; r++)
            unsafeAtomicAdd(&ovl.a.redB[q4 * 4 + r][e], accB[n][r]);
    }
    __syncthreads();   // all waves' M-loop (accC) + redB atomics complete
    // out1 scatter: col 64 + w'*3 + i = N0*(B_pre[w']*sh1[i] + C_pre[i][w']*sh0)
    for (int idx = tid; idx < 64 * 48; idx += 256) {
        int e = idx / 48;
        int cr = idx - e * 48;
        int wp = cr / 3;
        int i = cr - wp * 3;
        float val = N0_CONST * (ovl.a.redB[wp][e] * sh1_s[i][e] + ovl.a.accC[i * 16 + wp][e] * sh0_s[e]);
        unsafeAtomicAdd(&sums[src_s[e] * 112 + 64 + cr], val);
    }
    if (tid < 64) unsafeAtomicAdd(&cnt[src_s[tid]], 1.0f);
}

__global__ void k_final(const float* __restrict__ sums, const float* __restrict__ cnt,
                        const float* __restrict__ node_attr, float* __restrict__ out) {
    int idx = blockIdx.x * 256 + threadIdx.x;
    if (idx < N_NODES * 112) {
        int n = idx / 112;
        float c = fmaxf(cnt[n], 1.f);
        out[idx] = sums[idx] / c + node_attr[idx];
    }
}

extern "C" void kernel_launch(void* const* d_in, const int* in_sizes, int n_in,
                              void* d_out, int out_size, void* d_ws, size_t ws_size,
                              hipStream_t stream) {
    const float* node_attr  = (const float*)d_in[0];
    const int*   edge_index = (const int*)d_in[1];
    const float* edge_attr  = (const float*)d_in[2];
    const float* edge_sh    = (const float*)d_in[3];
    const float* W1         = (const float*)d_in[6];
    const float* b1         = (const float*)d_in[7];
    const float* W2         = (const float*)d_in[8];
    const float* b2         = (const float*)d_in[9];
    float* out = (float*)d_out;

    char* ws = (char*)d_ws;
    u16*   w2s  = (u16*)ws;                       // 6400*128*2 = 1,638,400
    u16*   w1t  = (u16*)(ws + 1638400);           // 128*128*2  =    32,768
    u16*   hgl  = (u16*)(ws + 1671168);           // 32768*128*2 = 8,388,608
    float* sums = (float*)(ws + 10059776);        // 4096*112*4 = 1,835,008
    float* cnt  = (float*)(ws + 11894784);        // 4096*4     =    16,384  (contiguous after sums)

    k_prep<<<416, 256, 0, stream>>>(W2, W1, w2s, w1t);
    k_h<<<512, 256, 0, stream>>>(edge_attr, w1t, b1, hgl, sums);
    k_main<<<512, 256, 0, stream>>>(w2s, hgl, b2, node_attr, edge_index, edge_sh, sums, cnt);
    k_final<<<1792, 256, 0, stream>>>(sums, cnt, node_attr, out);
}